// Round 1
// baseline (156.505 us; speedup 1.0000x reference)
//
#include <hip/hip_runtime.h>
#include <hip/hip_bf16.h>

// Problem constants (from reference)
constexpr int B = 16;
constexpr int N = 8192;
constexpr int H = 768;
constexpr int Q = 32;      // K_SEEDS
constexpr int K = 128;     // TOPK
#define SCALE 0.28867513459481287f   // 12^-0.5

// ---------------------------------------------------------------------------
// Kernel 1: scores[b*Q+q][n] = dot(input[b,n,:], seed[q,:])
// Grid 256 blocks x 512 threads. Each block owns 512 consecutive rows (b,n).
// Per wave: 8 rows x (qg octet of 8 q) accumulated in registers; lane layout
// hg = lane&15 (h-slice of 4 floats per 64-float chunk), qg = lane>>4.
// ---------------------------------------------------------------------------
__global__ __launch_bounds__(512, 2) void k_scores(const float* __restrict__ x,
                                                   const float* __restrict__ seed,
                                                   float* __restrict__ scores) {
  __shared__ __align__(16) float s_seed[Q * H];   // 96 KiB
  for (int i = threadIdx.x; i < Q * H / 4; i += 512)
    reinterpret_cast<float4*>(s_seed)[i] = reinterpret_cast<const float4*>(seed)[i];
  __syncthreads();

  const int wave = threadIdx.x >> 6;
  const int lane = threadIdx.x & 63;
  const int hg = lane & 15;
  const int qg = lane >> 4;

  for (int it = 0; it < 8; ++it) {
    const int row0 = (blockIdx.x << 9) + (it << 6) + (wave << 3);  // 8 rows
    const float* xp = x + (size_t)row0 * H;

    float acc[8][8];
#pragma unroll
    for (int r = 0; r < 8; ++r)
#pragma unroll
      for (int j = 0; j < 8; ++j) acc[r][j] = 0.f;

#pragma unroll 2
    for (int c = 0; c < 12; ++c) {
      const int h0 = (c << 6) + (hg << 2);
      float4 xv[8];
#pragma unroll
      for (int r = 0; r < 8; ++r)
        xv[r] = *reinterpret_cast<const float4*>(xp + r * H + h0);
#pragma unroll
      for (int j = 0; j < 8; ++j) {
        const float4 sv =
            *reinterpret_cast<const float4*>(&s_seed[(qg * 8 + j) * H + h0]);
#pragma unroll
        for (int r = 0; r < 8; ++r) {
          acc[r][j] = fmaf(xv[r].x, sv.x, acc[r][j]);
          acc[r][j] = fmaf(xv[r].y, sv.y, acc[r][j]);
          acc[r][j] = fmaf(xv[r].z, sv.z, acc[r][j]);
          acc[r][j] = fmaf(xv[r].w, sv.w, acc[r][j]);
        }
      }
    }

    // Value-splitting butterfly reduce across the 16 hg lanes.
    // Final: lane hg owns j = (hg>>1)&7, rows r = (hg&1)*4 + k (k=0..3),
    // values in statically-indexed v4[k].
    const bool up8 = (hg & 8) != 0;
    const bool up4 = (hg & 4) != 0;
    const bool up2 = (hg & 2) != 0;
    const bool up1 = (hg & 1) != 0;

    float t8[8][4];
#pragma unroll
    for (int r = 0; r < 8; ++r)
#pragma unroll
      for (int jj = 0; jj < 4; ++jj) {
        float send = up8 ? acc[r][jj] : acc[r][jj + 4];
        float recv = __shfl_xor(send, 8);
        float keep = up8 ? acc[r][jj + 4] : acc[r][jj];
        t8[r][jj] = keep + recv;
      }
    float t4[8][2];
#pragma unroll
    for (int r = 0; r < 8; ++r)
#pragma unroll
      for (int jj = 0; jj < 2; ++jj) {
        float send = up4 ? t8[r][jj] : t8[r][jj + 2];
        float recv = __shfl_xor(send, 4);
        float keep = up4 ? t8[r][jj + 2] : t8[r][jj];
        t4[r][jj] = keep + recv;
      }
    float t2[8];
#pragma unroll
    for (int r = 0; r < 8; ++r) {
      float send = up2 ? t4[r][0] : t4[r][1];
      float recv = __shfl_xor(send, 2);
      float keep = up2 ? t4[r][1] : t4[r][0];
      t2[r] = keep + recv;
    }
    float v4[4];
#pragma unroll
    for (int k = 0; k < 4; ++k) {
      float send = up1 ? t2[k] : t2[k + 4];
      float recv = __shfl_xor(send, 1);
      float keep = up1 ? t2[k + 4] : t2[k];
      v4[k] = keep + recv;
    }

    const int j = (hg >> 1) & 7;
    const int q = qg * 8 + j;
    const int row = row0;             // block stays within one batch
    const int b = row >> 13;
    const int n0 = (row & (N - 1)) + ((hg & 1) << 2);
    float4 o;
    o.x = v4[0]; o.y = v4[1]; o.z = v4[2]; o.w = v4[3];
    *reinterpret_cast<float4*>(scores + (((size_t)(b * Q + q)) << 13) + n0) = o;
  }
}

// ---------------------------------------------------------------------------
// Kernel 2: per (b,q) row: top-128 of 8192 scores -> softmax -> gather V.
// Grid 512 blocks x 256 threads.
// ---------------------------------------------------------------------------
__global__ __launch_bounds__(256) void k_topk(const float* __restrict__ scores,
                                              const float* __restrict__ x,
                                              float* __restrict__ out) {
  const int bq = blockIdx.x;
  const int b = bq >> 5;
  const int tid = threadIdx.x;
  const float* srow = scores + ((size_t)bq << 13);

  // Load 32 scores per thread; build monotonic uint keys.
  float f[32];
  uint32_t u[32];
  const float4* s4 = reinterpret_cast<const float4*>(srow);
#pragma unroll
  for (int i = 0; i < 8; ++i) {
    float4 v = s4[i * 256 + tid];
    f[i * 4 + 0] = v.x; f[i * 4 + 1] = v.y;
    f[i * 4 + 2] = v.z; f[i * 4 + 3] = v.w;
  }
#pragma unroll
  for (int e = 0; e < 32; ++e) {
    uint32_t bits = __float_as_uint(f[e]);
    u[e] = (bits & 0x80000000u) ? ~bits : (bits | 0x80000000u);
  }

  // Binary search smallest T with count(u > T) < K.
  __shared__ int s_red[4];
  uint32_t lo = 0u, hi = 0xFFFFFFFFu;
  while (lo < hi) {
    uint32_t mid = lo + ((hi - lo) >> 1);
    int cnt = 0;
#pragma unroll
    for (int e = 0; e < 32; ++e) cnt += (u[e] > mid) ? 1 : 0;
#pragma unroll
    for (int m = 1; m < 64; m <<= 1) cnt += __shfl_xor(cnt, m);
    if ((tid & 63) == 0) s_red[tid >> 6] = cnt;
    __syncthreads();
    cnt = s_red[0] + s_red[1] + s_red[2] + s_red[3];
    if (cnt >= K) lo = mid + 1; else hi = mid;
    __syncthreads();
  }
  const uint32_t T = lo;

  // Collect strictly-greater, then lowest-index ties == T.
  __shared__ int s_cnt, s_eqn;
  __shared__ int s_idx[K];
  __shared__ float s_w[K];
  __shared__ int s_eq[256];
  __shared__ float s_m, s_sum;
  if (tid == 0) { s_cnt = 0; s_eqn = 0; }
  __syncthreads();
#pragma unroll
  for (int e = 0; e < 32; ++e) {
    int n = ((e >> 2) << 10) + (tid << 2) + (e & 3);
    if (u[e] > T) {
      int p = atomicAdd(&s_cnt, 1);
      s_idx[p] = n;
      s_w[p] = f[e];
    } else if (u[e] == T) {
      int p = atomicAdd(&s_eqn, 1);
      if (p < 256) s_eq[p] = n;
    }
  }
  __syncthreads();
  const int c1 = s_cnt;
  const int need = K - c1;
  if (tid == 0 && need > 0) {
    uint32_t tb = (T & 0x80000000u) ? (T ^ 0x80000000u) : ~T;
    float tf = __uint_as_float(tb);
    int m = s_eqn; if (m > 256) m = 256;
    for (int a = 0; a < need; ++a) {       // selection-sort lowest indices
      int best = s_eq[a], bi = a;
      for (int z = a + 1; z < m; ++z)
        if (s_eq[z] < best) { best = s_eq[z]; bi = z; }
      s_eq[bi] = s_eq[a]; s_eq[a] = best;
      s_idx[c1 + a] = best;
      s_w[c1 + a] = tf;
    }
  }
  __syncthreads();

  // Softmax over the 128 selected values (store un-normalized exp in s_w).
  if (tid < 64) {
    float v = fmaxf(s_w[tid], s_w[tid + 64]);
#pragma unroll
    for (int m = 1; m < 64; m <<= 1) v = fmaxf(v, __shfl_xor(v, m));
    if (tid == 0) s_m = v;
  }
  __syncthreads();
  const float mx = s_m * SCALE;
  if (tid < K) s_w[tid] = __expf(s_w[tid] * SCALE - mx);
  __syncthreads();
  if (tid < 64) {
    float v = s_w[tid] + s_w[tid + 64];
#pragma unroll
    for (int m = 1; m < 64; m <<= 1) v += __shfl_xor(v, m);
    if (tid == 0) s_sum = v;
  }
  __syncthreads();

  // Gather + weighted sum: 192 threads x float4 = 768 floats.
  if (tid < 192) {
    const float4* xb =
        reinterpret_cast<const float4*>(x + ((size_t)b << 13) * H);
    float4 acc = make_float4(0.f, 0.f, 0.f, 0.f);
#pragma unroll 4
    for (int k = 0; k < K; ++k) {
      float w = s_w[k];
      int row = s_idx[k];
      float4 v = xb[(size_t)row * (H / 4) + tid];
      acc.x = fmaf(w, v.x, acc.x);
      acc.y = fmaf(w, v.y, acc.y);
      acc.z = fmaf(w, v.z, acc.z);
      acc.w = fmaf(w, v.w, acc.w);
    }
    const float inv = 1.f / s_sum;
    float4 o;
    o.x = acc.x * inv; o.y = acc.y * inv; o.z = acc.z * inv; o.w = acc.w * inv;
    reinterpret_cast<float4*>(out)[(size_t)bq * (H / 4) + tid] = o;
  }
}

extern "C" void kernel_launch(void* const* d_in, const int* in_sizes, int n_in,
                              void* d_out, int out_size, void* d_ws, size_t ws_size,
                              hipStream_t stream) {
  const float* x = (const float*)d_in[0];     // [B, N, H] f32
  const float* seed = (const float*)d_in[1];  // [1, Q, H] f32
  float* out = (float*)d_out;                 // [B, Q, H] f32
  float* scores = (float*)d_ws;               // [B*Q, N] f32 = 16 MiB scratch

  k_scores<<<256, 512, 0, stream>>>(x, seed, scores);
  k_topk<<<512, 256, 0, stream>>>(scores, x, out);
}